// Round 9
// baseline (425.331 us; speedup 1.0000x reference)
//
#include <hip/hip_runtime.h>

typedef __attribute__((ext_vector_type(8))) short bf16x8;
typedef __attribute__((ext_vector_type(4))) float f32x4;

// Operand-swapped GEMM: D^T = W (A-operand) * h^T (B-operand).
// K-SPLIT over wave pairs: wave w (group A, w<4) and wave w+4 (group B) compute
// the same 16-col output stripe; A handles K 0-31, B handles K 32-63 (hi & lo).
// Partial f32x4 sums are exchanged through LDS once per phase.
#define MFMA(a, b, c) __builtin_amdgcn_mfma_f32_16x16x32_bf16((a), (b), (c), 0, 0, 0)

__device__ __forceinline__ short f2bf(float f) {
    union { float f; unsigned u; } v; v.f = f;
    unsigned r = v.u + 0x7fffu + ((v.u >> 16) & 1u);   // RNE
    return (short)(r >> 16);
}
__device__ __forceinline__ float bf2f(short h) {
    union { unsigned u; float f; } v;
    v.u = ((unsigned)(unsigned short)h) << 16;
    return v.f;
}
__device__ __forceinline__ void wsplit(float w, short& hi, short& lo) {
    hi = f2bf(w);
    lo = f2bf(w - bf2f(hi));
}
__device__ __forceinline__ float tanh_fast(float x) {
    float z = __builtin_amdgcn_exp2f(x * 2.8853900817779268f); // 2*log2(e)
    return 1.0f - 2.0f * __builtin_amdgcn_rcpf(z + 1.0f);
}
__device__ __forceinline__ unsigned cvt_pk_bf16(float a, float b) {
    unsigned r;
    asm("v_cvt_pk_bf16_f32 %0, %1, %2" : "=v"(r) : "v"(a), "v"(b));
    return r;
}

// weight fragment pair (hi + bf16 residual): element i = W[jrow][kbase+i], zero-padded
__device__ __forceinline__ void makeA2(const float* __restrict__ W, int jrow, int kbase,
                                       bf16x8& Ahi, bf16x8& Alo) {
#pragma unroll
    for (int i = 0; i < 8; ++i) {
        int m = kbase + i;
        short h = 0, l = 0;
        if (jrow < 50 && m < 50) wsplit(W[jrow * 50 + m], h, l);
        Ahi[i] = h; Alo[i] = l;
    }
}

// --- LDS h tile: [16 batch][128 hidden] bf16 (256B rows); cols 0-63 hi, 64-127 lo.
// XOR-swizzle bits 4-7 of byte-in-row with row (bijective).
// swz(row, b ^ 128) == swz(row, b) ^ 128 -> lo offset derived by XOR on the
// INTEGER offset (never +128, never XOR on a flat pointer).
__device__ __forceinline__ int swz(int row, int byteInRow) {
    return (row << 8) + (byteInRow ^ ((row & 15) << 4));
}
__device__ __forceinline__ float ldsR(const short* buf, int row, int col) {
    return bf2f(*(const short*)((const char*)buf + swz(row, col << 1)));
}

// store 4 consecutive hidden cols (hi + lo residual) for this lane's batch row.
__device__ __forceinline__ void storeT(short* buf, int off, float t0, float t1, float t2, float t3) {
    unsigned h01 = cvt_pk_bf16(t0, t1);
    unsigned h23 = cvt_pk_bf16(t2, t3);
    float r0 = t0 - bf2f((short)h01);
    float r1 = t1 - bf2f((short)(h01 >> 16));
    float r2 = t2 - bf2f((short)h23);
    float r3 = t3 - bf2f((short)(h23 >> 16));
    unsigned l01 = cvt_pk_bf16(r0, r1);
    unsigned l23 = cvt_pk_bf16(r2, r3);
    uint2 hv; hv.x = h01; hv.y = h23;
    uint2 lv; lv.x = l01; lv.y = l23;
    *(uint2*)((char*)buf + off)         = hv;
    *(uint2*)((char*)buf + (off ^ 128)) = lv;
}

// One K-split phase. Z2/Z3: write zeros for h2/h3 output (pipeline fill).
// reads r* (prev parity), writes w* (this parity). Two barriers:
// [reads + 15 MFMAs + partial writes] BAR [combine + tanh + stores] BAR.
template<bool Z2, bool Z3>
__device__ __forceinline__ void phase8(
    const short* r1, const short* r2, const short* r3,
    short* w1, short* w2, short* w3,
    f32x4* part, int wq, bool isA,
    int oh, int ol, int wbyte, int lane, float xf,
    const f32x4& b1v, const f32x4& b2v, const f32x4& b3v, const f32x4& w1f,
    const bf16x8& A1h, const bf16x8& A1l,
    const bf16x8& I2h, const bf16x8& I2l, const bf16x8& H2h, const bf16x8& H2l,
    const bf16x8& I3h, const bf16x8& I3l, const bf16x8& H3h, const bf16x8& H3l)
{
    bf16x8 s1h = *(const bf16x8*)((const char*)r1 + oh);
    bf16x8 s1l = *(const bf16x8*)((const char*)r1 + ol);
    bf16x8 f2h = *(const bf16x8*)((const char*)r2 + oh);
    bf16x8 f2l = *(const bf16x8*)((const char*)r2 + ol);
    bf16x8 s3h = *(const bf16x8*)((const char*)r3 + oh);
    bf16x8 s3l = *(const bf16x8*)((const char*)r3 + ol);

    f32x4 c1i;
    c1i[0] = fmaf(w1f[0], xf, b1v[0]);
    c1i[1] = fmaf(w1f[1], xf, b1v[1]);
    c1i[2] = fmaf(w1f[2], xf, b1v[2]);
    c1i[3] = fmaf(w1f[3], xf, b1v[3]);

    f32x4 z = {0.f, 0.f, 0.f, 0.f};
    f32x4 p0 = isA ? b2v : z, p1 = z;   // L2 chains (bias once, in A)
    f32x4 q0 = isA ? z : b3v, q1 = z;   // L3 chains (bias once, in B)
    f32x4 u0 = isA ? z : c1i;           // L1 chain  (x+bias once, in B)

    // 15 MFMAs, 5 chains of depth 3, round-robin
    p0 = MFMA(I2h, s1h, p0);  q0 = MFMA(I3h, f2h, q0);  u0 = MFMA(A1h, s1h, u0);
    p1 = MFMA(H2h, f2h, p1);  q1 = MFMA(H3h, s3h, q1);
    p0 = MFMA(I2l, s1h, p0);  q0 = MFMA(I3l, f2h, q0);  u0 = MFMA(A1l, s1h, u0);
    p1 = MFMA(H2l, f2h, p1);  q1 = MFMA(H3l, s3h, q1);
    p0 = MFMA(I2h, s1l, p0);  q0 = MFMA(I3h, f2l, q0);  u0 = MFMA(A1h, s1l, u0);
    p1 = MFMA(H2h, f2l, p1);  q1 = MFMA(H3h, s3l, q1);

    const int pi = (wq << 6) + lane;   // [4][64] slot within a layer region
    if (isA) {
        part[256 + pi] = q0 + q1;      // L3 partial (region 1)
        part[512 + pi] = u0;           // L1 partial (region 2)
    } else {
        part[pi] = p0 + p1;            // L2 partial (region 0)
    }
    __syncthreads();   // partials visible

    if (isA) {
        if (Z2) {
            storeT(w2, wbyte, 0.f, 0.f, 0.f, 0.f);
        } else {
            f32x4 pb = part[pi];
            float t0 = tanh_fast(p0[0] + p1[0] + pb[0]);
            float t1 = tanh_fast(p0[1] + p1[1] + pb[1]);
            float t2 = tanh_fast(p0[2] + p1[2] + pb[2]);
            float t3 = tanh_fast(p0[3] + p1[3] + pb[3]);
            storeT(w2, wbyte, t0, t1, t2, t3);
        }
    } else {
        if (Z3) {
            storeT(w3, wbyte, 0.f, 0.f, 0.f, 0.f);
        } else {
            f32x4 qa = part[256 + pi];
            float t0 = tanh_fast(q0[0] + q1[0] + qa[0]);
            float t1 = tanh_fast(q0[1] + q1[1] + qa[1]);
            float t2 = tanh_fast(q0[2] + q1[2] + qa[2]);
            float t3 = tanh_fast(q0[3] + q1[3] + qa[3]);
            storeT(w3, wbyte, t0, t1, t2, t3);
        }
        f32x4 ua = part[512 + pi];
        float t0 = tanh_fast(u0[0] + ua[0]);
        float t1 = tanh_fast(u0[1] + ua[1]);
        float t2 = tanh_fast(u0[2] + ua[2]);
        float t3 = tanh_fast(u0[3] + ua[3]);
        storeT(w1, wbyte, t0, t1, t2, t3);
    }
    __syncthreads();   // h(this parity) complete
}

__global__ __launch_bounds__(512, 1)
void rnn3_kernel(const float* __restrict__ x,
                 const float* __restrict__ Wih1, const float* __restrict__ Whh1,
                 const float* __restrict__ bih1, const float* __restrict__ bhh1,
                 const float* __restrict__ Wih2, const float* __restrict__ Whh2,
                 const float* __restrict__ bih2, const float* __restrict__ bhh2,
                 const float* __restrict__ Wih3, const float* __restrict__ Whh3,
                 const float* __restrict__ bih3, const float* __restrict__ bhh3,
                 const float* __restrict__ Wfc,  const float* __restrict__ bfc,
                 float* __restrict__ out)
{
    __shared__ __align__(16) short h1s[2][2048];
    __shared__ __align__(16) short h2s[2][2048];
    __shared__ __align__(16) short h3s[2][2048];
    __shared__ float xls[512 * 17 + 64];           // x f32, stride-17; zeroed tail
    __shared__ __align__(16) f32x4 part[3 * 4 * 64]; // partial sums [layer][wq][lane]

    const int tid  = threadIdx.x;
    const int lane = tid & 63;
    const int w    = tid >> 6;        // 0..7
    const int wq   = w & 3;           // col-stripe id
    const bool isA = w < 4;           // K 0-31 group vs K 32-63 group
    const int g    = lane >> 4;
    const int l15  = lane & 15;
    const int jrow = (wq << 4) | l15;        // weight row (output col)
    const int bcol = l15;                    // batch row
    const int jout0 = (wq << 4) + (g << 2);  // lane's 4 output hidden cols
    const int b0   = blockIdx.x * 16;

    // ---- zero-init all h buffers (both parities = h(-1)=0 and fill-safety) ----
    { int* z1 = (int*)h1s; int* z2 = (int*)h2s; int* z3 = (int*)h3s;
      for (int k = tid; k < 2048; k += 512) { z1[k] = 0; z2[k] = 0; z3[k] = 0; } }

    // ---- stage x as f32 [t][b] (stride 17), zero the drain tail ----
    {
        const float4* xg = (const float4*)(x + (size_t)b0 * 512);
        for (int idx = tid; idx < 2048; idx += 512) {
            float4 v = xg[idx];
            int b = idx >> 7, t0 = (idx & 127) << 2;
            xls[(t0 + 0) * 17 + b] = v.x;
            xls[(t0 + 1) * 17 + b] = v.y;
            xls[(t0 + 2) * 17 + b] = v.z;
            xls[(t0 + 3) * 17 + b] = v.w;
        }
        if (tid < 64) xls[512 * 17 + tid] = 0.0f;   // phases 512/513 read here
    }

    // ---- per-wave half-K weight fragments (hi + lo residual) ----
    const int kbase = (isA ? 0 : 32) + (g << 3);
    bf16x8 A1h, A1l, I2h, I2l, H2h, H2l, I3h, I3l, H3h, H3l;
    makeA2(Whh1, jrow, kbase, A1h, A1l);
    makeA2(Wih2, jrow, kbase, I2h, I2l);
    makeA2(Whh2, jrow, kbase, H2h, H2l);
    makeA2(Wih3, jrow, kbase, I3h, I3l);
    makeA2(Whh3, jrow, kbase, H3h, H3l);

    f32x4 b1v, b2v, b3v, w1f;
#pragma unroll
    for (int r = 0; r < 4; ++r) {
        int j = jout0 + r;
        bool v = j < 50;
        b1v[r] = v ? (bih1[j] + bhh1[j]) : 0.0f;
        b2v[r] = v ? (bih2[j] + bhh2[j]) : 0.0f;
        b3v[r] = v ? (bih3[j] + bhh3[j]) : 0.0f;
        w1f[r] = v ? Wih1[j] : 0.0f;
    }

    const int wbyte = swz(bcol, jout0 << 1);
    // loop-invariant state-read byte offsets (this wave's K-half, hi and lo)
    const int oh = swz(bcol, ((isA ? 0 : 1) << 6) + (g << 4));
    const int ol = swz(bcol, ((isA ? 2 : 3) << 6) + (g << 4));

    __syncthreads();   // x staged, h zeroed

    // phase i: reads parity (i+1)&1, writes parity i&1.
    // phase 0: L1(0) real, L2/L3 outputs forced to zero (= h(-1) states)
    phase8<true, true>(h1s[1], h2s[1], h3s[1], h1s[0], h2s[0], h3s[0],
                       part, wq, isA, oh, ol, wbyte, lane, xls[bcol],
                       b1v, b2v, b3v, w1f,
                       A1h, A1l, I2h, I2l, H2h, H2l, I3h, I3l, H3h, H3l);
    // phase 1: L1(1), L2(0) real; L3 zero
    phase8<false, true>(h1s[0], h2s[0], h3s[0], h1s[1], h2s[1], h3s[1],
                        part, wq, isA, oh, ol, wbyte, lane, xls[17 + bcol],
                        b1v, b2v, b3v, w1f,
                        A1h, A1l, I2h, I2l, H2h, H2l, I3h, I3l, H3h, H3l);

    // main phases 2..511 (manual 2x unroll, compile-time parities)
    for (int i = 2; i < 512; i += 2) {
        phase8<false, false>(h1s[1], h2s[1], h3s[1], h1s[0], h2s[0], h3s[0],
                             part, wq, isA, oh, ol, wbyte, lane, xls[i * 17 + bcol],
                             b1v, b2v, b3v, w1f,
                             A1h, A1l, I2h, I2l, H2h, H2l, I3h, I3l, H3h, H3l);
        phase8<false, false>(h1s[0], h2s[0], h3s[0], h1s[1], h2s[1], h3s[1],
                             part, wq, isA, oh, ol, wbyte, lane, xls[(i + 1) * 17 + bcol],
                             b1v, b2v, b3v, w1f,
                             A1h, A1l, I2h, I2l, H2h, H2l, I3h, I3l, H3h, H3l);
    }

    // drain: phase 512 (L2(511), L3(510); L1 garbage but finite - x tail zeroed)
    phase8<false, false>(h1s[1], h2s[1], h3s[1], h1s[0], h2s[0], h3s[0],
                         part, wq, isA, oh, ol, wbyte, lane, xls[512 * 17 + bcol],
                         b1v, b2v, b3v, w1f,
                         A1h, A1l, I2h, I2l, H2h, H2l, I3h, I3l, H3h, H3l);
    // drain: phase 513 (L3(511) -> h3s[1]; other outputs unused)
    phase8<false, false>(h1s[0], h2s[0], h3s[0], h1s[1], h2s[1], h3s[1],
                         part, wq, isA, oh, ol, wbyte, lane, xls[513 * 17 + bcol],
                         b1v, b2v, b3v, w1f,
                         A1h, A1l, I2h, I2l, H2h, H2l, I3h, I3l, H3h, H3l);

    // ---- FC epilogue: out[b][o] = (h3_hi + h3_lo) @ Wfc^T + bfc ----
    if (w < 4) {
        const short* h3f = h3s[1];
        int o = (w << 2) | g;           // 0..15, valid < 10
        int b = bcol;
        if (o < 10) {
            float acc = bfc[o];
            for (int k = 0; k < 50; ++k)
                acc += (ldsR(h3f, b, k) + ldsR(h3f, b, 64 + k)) * Wfc[o * 50 + k];
            out[(size_t)(b0 + b) * 10 + o] = acc;
        }
    }
}

extern "C" void kernel_launch(void* const* d_in, const int* in_sizes, int n_in,
                              void* d_out, int out_size, void* d_ws, size_t ws_size,
                              hipStream_t stream) {
    const float* x    = (const float*)d_in[0];
    const float* Wih1 = (const float*)d_in[1];
    const float* Whh1 = (const float*)d_in[2];
    const float* bih1 = (const float*)d_in[3];
    const float* bhh1 = (const float*)d_in[4];
    const float* Wih2 = (const float*)d_in[5];
    const float* Whh2 = (const float*)d_in[6];
    const float* bih2 = (const float*)d_in[7];
    const float* bhh2 = (const float*)d_in[8];
    const float* Wih3 = (const float*)d_in[9];
    const float* Whh3 = (const float*)d_in[10];
    const float* bih3 = (const float*)d_in[11];
    const float* bhh3 = (const float*)d_in[12];
    const float* Wfc  = (const float*)d_in[13];
    const float* bfc  = (const float*)d_in[14];
    float* out = (float*)d_out;

    dim3 grid(256), block(512);   // 16 batch rows/block; 8 waves = K-split pairs
    hipLaunchKernelGGL(rnn3_kernel, grid, block, 0, stream,
                       x, Wih1, Whh1, bih1, bhh1,
                       Wih2, Whh2, bih2, bhh2,
                       Wih3, Whh3, bih3, bhh3,
                       Wfc, bfc, out);
}

// Round 10
// 315.959 us; speedup vs baseline: 1.3462x; 1.3462x over previous
//
#include <hip/hip_runtime.h>

typedef __attribute__((ext_vector_type(8))) short bf16x8;
typedef __attribute__((ext_vector_type(4))) float f32x4;

// Operand-swapped GEMM: D^T = W (A-operand) * h^T (B-operand).
// WAVE SPECIALIZATION: 12 waves = {L1,L2,L3} x 4 col-stripes. Each wave owns
// one layer's full K=64 for its 16 output cols -> no cross-wave exchange,
// ONE barrier per phase. C-frag = 4 consecutive hidden cols for one batch row
// -> contiguous b64 LDS writes (hi at off, lo at off XOR 128).
#define MFMA(a, b, c) __builtin_amdgcn_mfma_f32_16x16x32_bf16((a), (b), (c), 0, 0, 0)

__device__ __forceinline__ short f2bf(float f) {
    union { float f; unsigned u; } v; v.f = f;
    unsigned r = v.u + 0x7fffu + ((v.u >> 16) & 1u);   // RNE
    return (short)(r >> 16);
}
__device__ __forceinline__ float bf2f(short h) {
    union { unsigned u; float f; } v;
    v.u = ((unsigned)(unsigned short)h) << 16;
    return v.f;
}
__device__ __forceinline__ void wsplit(float w, short& hi, short& lo) {
    hi = f2bf(w);
    lo = f2bf(w - bf2f(hi));
}
__device__ __forceinline__ float tanh_fast(float x) {
    float z = __builtin_amdgcn_exp2f(x * 2.8853900817779268f); // 2*log2(e)
    return 1.0f - 2.0f * __builtin_amdgcn_rcpf(z + 1.0f);
}
__device__ __forceinline__ unsigned cvt_pk_bf16(float a, float b) {
    unsigned r;
    asm("v_cvt_pk_bf16_f32 %0, %1, %2" : "=v"(r) : "v"(a), "v"(b));
    return r;
}

// weight fragment pair (hi + bf16 residual): element i = W[jrow][kbase+i], zero-padded
__device__ __forceinline__ void makeA2(const float* __restrict__ W, int jrow, int kbase,
                                       bf16x8& Ahi, bf16x8& Alo) {
#pragma unroll
    for (int i = 0; i < 8; ++i) {
        int m = kbase + i;
        short h = 0, l = 0;
        if (jrow < 50 && m < 50) wsplit(W[jrow * 50 + m], h, l);
        Ahi[i] = h; Alo[i] = l;
    }
}

// --- LDS h tile: [16 batch][128 hidden] bf16 (256B rows); cols 0-63 hi, 64-127 lo.
// XOR-swizzle bits 4-7 of byte-in-row with row (bijective).
// swz(row, b ^ 128) == swz(row, b) ^ 128 -> lo offset derived by XOR on the
// INTEGER offset (never +128, never XOR on a flat pointer).
__device__ __forceinline__ int swz(int row, int byteInRow) {
    return (row << 8) + (byteInRow ^ ((row & 15) << 4));
}
__device__ __forceinline__ bf16x8 ldsA(const short* buf, int row, int kblk, int g) {
    return *(const bf16x8*)((const char*)buf + swz(row, (kblk << 6) + (g << 4)));
}
__device__ __forceinline__ float ldsR(const short* buf, int row, int col) {
    return bf2f(*(const short*)((const char*)buf + swz(row, col << 1)));
}

// store 4 consecutive hidden cols (hi + lo residual) for this lane's batch row.
__device__ __forceinline__ void storeT(short* buf, int off, float t0, float t1, float t2, float t3) {
    unsigned h01 = cvt_pk_bf16(t0, t1);
    unsigned h23 = cvt_pk_bf16(t2, t3);
    float r0 = t0 - bf2f((short)h01);
    float r1 = t1 - bf2f((short)(h01 >> 16));
    float r2 = t2 - bf2f((short)h23);
    float r3 = t3 - bf2f((short)(h23 >> 16));
    unsigned l01 = cvt_pk_bf16(r0, r1);
    unsigned l23 = cvt_pk_bf16(r2, r3);
    uint2 hv; hv.x = h01; hv.y = h23;
    uint2 lv; lv.x = l01; lv.y = l23;
    *(uint2*)((char*)buf + off)         = hv;
    *(uint2*)((char*)buf + (off ^ 128)) = lv;
}
__device__ __forceinline__ void storeZ(short* buf, int off) {
    uint2 zz; zz.x = 0u; zz.y = 0u;
    *(uint2*)((char*)buf + off)         = zz;
    *(uint2*)((char*)buf + (off ^ 128)) = zz;
}

// Full two-matrix layer for one wave: 12 MFMAs, 4 chains of 3.
// Bias enters as the C operand of the first MFMA (no accumulator-init movs).
template<bool ZOUT>
__device__ __forceinline__ void layerW_full(
    const short* rIn, const short* rState, short* wOut,
    int bcol, int g, int wbyte,
    const bf16x8& Ih0, const bf16x8& Ih1, const bf16x8& Il0, const bf16x8& Il1,
    const bf16x8& Hh0, const bf16x8& Hh1, const bf16x8& Hl0, const bf16x8& Hl1,
    const f32x4& bias, const f32x4& zc)
{
    bf16x8 i0 = ldsA(rIn, bcol, 0, g), i1 = ldsA(rIn, bcol, 1, g);
    bf16x8 i2 = ldsA(rIn, bcol, 2, g), i3 = ldsA(rIn, bcol, 3, g);
    bf16x8 s0 = ldsA(rState, bcol, 0, g), s1 = ldsA(rState, bcol, 1, g);
    bf16x8 s2 = ldsA(rState, bcol, 2, g), s3 = ldsA(rState, bcol, 3, g);
    f32x4 a0 = MFMA(Ih0, i0, bias);
    f32x4 a1 = MFMA(Hh0, s0, zc);
    f32x4 a2 = MFMA(Ih0, i2, zc);
    f32x4 a3 = MFMA(Hh0, s2, zc);
    a0 = MFMA(Ih1, i1, a0);
    a1 = MFMA(Hh1, s1, a1);
    a2 = MFMA(Ih1, i3, a2);
    a3 = MFMA(Hh1, s3, a3);
    a0 = MFMA(Hl0, s0, a0);
    a1 = MFMA(Il0, i0, a1);
    a2 = MFMA(Hl1, s1, a2);
    a3 = MFMA(Il1, i1, a3);
    if (ZOUT) {
        storeZ(wOut, wbyte);
    } else {
        float t0 = tanh_fast((a0[0] + a1[0]) + (a2[0] + a3[0]));
        float t1 = tanh_fast((a0[1] + a1[1]) + (a2[1] + a3[1]));
        float t2 = tanh_fast((a0[2] + a1[2]) + (a2[2] + a3[2]));
        float t3 = tanh_fast((a0[3] + a1[3]) + (a2[3] + a3[3]));
        storeT(wOut, wbyte, t0, t1, t2, t3);
    }
}

// L1 layer for one wave: 6 MFMAs, 3 chains of 2; x term pre-folded into c1i.
__device__ __forceinline__ void layerW_one(
    const short* r1, short* w1,
    int bcol, int g, int wbyte,
    const bf16x8& Hh0, const bf16x8& Hh1, const bf16x8& Hl0, const bf16x8& Hl1,
    const f32x4& c1i, const f32x4& zc)
{
    bf16x8 s0 = ldsA(r1, bcol, 0, g), s1 = ldsA(r1, bcol, 1, g);
    bf16x8 s2 = ldsA(r1, bcol, 2, g), s3 = ldsA(r1, bcol, 3, g);
    f32x4 u0 = MFMA(Hh0, s0, c1i);
    f32x4 u1 = MFMA(Hh0, s2, zc);
    f32x4 u2 = MFMA(Hl0, s0, zc);
    u0 = MFMA(Hh1, s1, u0);
    u1 = MFMA(Hh1, s3, u1);
    u2 = MFMA(Hl1, s1, u2);
    float t0 = tanh_fast(u0[0] + u1[0] + u2[0]);
    float t1 = tanh_fast(u0[1] + u1[1] + u2[1]);
    float t2 = tanh_fast(u0[2] + u1[2] + u2[2]);
    float t3 = tanh_fast(u0[3] + u1[3] + u2[3]);
    storeT(w1, wbyte, t0, t1, t2, t3);
}

// One phase: wave-uniform dispatch by layerid, ONE barrier at the end.
// reads r* (prev parity), writes w* (this parity).
template<bool Z2, bool Z3>
__device__ __forceinline__ void phaseW(
    const short* r1, const short* r2, const short* r3,
    short* w1, short* w2, short* w3,
    int layerid, int bcol, int g, int wbyte, const float* xrow,
    const f32x4& bv, const f32x4& w1f,
    const bf16x8& Ih0, const bf16x8& Ih1, const bf16x8& Il0, const bf16x8& Il1,
    const bf16x8& Hh0, const bf16x8& Hh1, const bf16x8& Hl0, const bf16x8& Hl1,
    const f32x4& zc)
{
    if (layerid == 0) {
        float xf = xrow[bcol];
        f32x4 c1i;
        c1i[0] = fmaf(w1f[0], xf, bv[0]);
        c1i[1] = fmaf(w1f[1], xf, bv[1]);
        c1i[2] = fmaf(w1f[2], xf, bv[2]);
        c1i[3] = fmaf(w1f[3], xf, bv[3]);
        layerW_one(r1, w1, bcol, g, wbyte, Hh0, Hh1, Hl0, Hl1, c1i, zc);
    } else if (layerid == 1) {
        // L2(i-1): input h1(prev), state h2(prev)
        layerW_full<Z2>(r1, r2, w2, bcol, g, wbyte,
                        Ih0, Ih1, Il0, Il1, Hh0, Hh1, Hl0, Hl1, bv, zc);
    } else {
        // L3(i-2): input h2(prev), state h3(prev)
        layerW_full<Z3>(r2, r3, w3, bcol, g, wbyte,
                        Ih0, Ih1, Il0, Il1, Hh0, Hh1, Hl0, Hl1, bv, zc);
    }
    __syncthreads();
}

__global__ __launch_bounds__(768, 1)
void rnn3_kernel(const float* __restrict__ x,
                 const float* __restrict__ Wih1, const float* __restrict__ Whh1,
                 const float* __restrict__ bih1, const float* __restrict__ bhh1,
                 const float* __restrict__ Wih2, const float* __restrict__ Whh2,
                 const float* __restrict__ bih2, const float* __restrict__ bhh2,
                 const float* __restrict__ Wih3, const float* __restrict__ Whh3,
                 const float* __restrict__ bih3, const float* __restrict__ bhh3,
                 const float* __restrict__ Wfc,  const float* __restrict__ bfc,
                 float* __restrict__ out)
{
    __shared__ __align__(16) short h1s[2][2048];
    __shared__ __align__(16) short h2s[2][2048];
    __shared__ __align__(16) short h3s[2][2048];
    __shared__ float xls[514 * 17 + 8];   // x f32 stride-17; tail (phases 512/513) zeroed

    const int tid  = threadIdx.x;
    const int lane = tid & 63;
    const int w    = tid >> 6;        // 0..11
    const int stripe  = w & 3;        // 16-col output stripe
    const int layerid = w >> 2;       // 0 = L1, 1 = L2, 2 = L3
    const int g    = lane >> 4;
    const int l15  = lane & 15;
    const int jrow = (stripe << 4) | l15;      // weight row (output col)
    const int bcol = l15;                      // batch row
    const int jout0 = (stripe << 4) + (g << 2);
    const int b0   = blockIdx.x * 16;

    // ---- zero-init all h buffers (h(-1)=0 + fill safety) ----
    { int* z1 = (int*)h1s; int* z2 = (int*)h2s; int* z3 = (int*)h3s;
      for (int k = tid; k < 2048; k += 768) { z1[k] = 0; z2[k] = 0; z3[k] = 0; } }

    // ---- stage x as f32 [t][b] (stride 17); zero the drain tail ----
    {
        const float4* xg = (const float4*)(x + (size_t)b0 * 512);
        for (int idx = tid; idx < 2048; idx += 768) {
            float4 v = xg[idx];
            int b = idx >> 7, t0 = (idx & 127) << 2;
            xls[(t0 + 0) * 17 + b] = v.x;
            xls[(t0 + 1) * 17 + b] = v.y;
            xls[(t0 + 2) * 17 + b] = v.z;
            xls[(t0 + 3) * 17 + b] = v.w;
        }
        if (tid < 42) xls[512 * 17 + tid] = 0.0f;   // covers 512*17 .. 514*17+7
    }

    // ---- per-wave weights: ONLY this wave's layer (8 frags = 32 VGPRs) ----
    const float* WI; const float* WH; const float* bi; const float* bh;
    if (layerid == 0)      { WI = Wih1; WH = Whh1; bi = bih1; bh = bhh1; }
    else if (layerid == 1) { WI = Wih2; WH = Whh2; bi = bih2; bh = bhh2; }
    else                   { WI = Wih3; WH = Whh3; bi = bih3; bh = bhh3; }

    bf16x8 zf8 = {0,0,0,0,0,0,0,0};
    bf16x8 Ih0 = zf8, Il0 = zf8, Ih1 = zf8, Il1 = zf8;
    bf16x8 Hh0, Hl0, Hh1, Hl1;
    makeA2(WH, jrow, (g << 3),      Hh0, Hl0);
    makeA2(WH, jrow, 32 + (g << 3), Hh1, Hl1);
    if (layerid != 0) {
        makeA2(WI, jrow, (g << 3),      Ih0, Il0);
        makeA2(WI, jrow, 32 + (g << 3), Ih1, Il1);
    }

    f32x4 bv, w1f;
#pragma unroll
    for (int r = 0; r < 4; ++r) {
        int j = jout0 + r;
        bool v = j < 50;
        bv[r]  = v ? (bi[j] + bh[j]) : 0.0f;
        w1f[r] = (layerid == 0 && v) ? Wih1[j] : 0.0f;
    }
    const f32x4 zc = {0.f, 0.f, 0.f, 0.f};

    const int wbyte = swz(bcol, jout0 << 1);

    __syncthreads();   // x staged, h zeroed

    // phase i: reads parity (i+1)&1, writes parity i&1.
    // phase 0: L1(0) real; L2/L3 write zeros (= h(-1) states)
    phaseW<true, true>(h1s[1], h2s[1], h3s[1], h1s[0], h2s[0], h3s[0],
                       layerid, bcol, g, wbyte, &xls[0],
                       bv, w1f, Ih0, Ih1, Il0, Il1, Hh0, Hh1, Hl0, Hl1, zc);
    // phase 1: L1(1), L2(0) real; L3 writes zero
    phaseW<false, true>(h1s[0], h2s[0], h3s[0], h1s[1], h2s[1], h3s[1],
                        layerid, bcol, g, wbyte, &xls[17],
                        bv, w1f, Ih0, Ih1, Il0, Il1, Hh0, Hh1, Hl0, Hl1, zc);

    // main phases 2..511 (manual 2x unroll, compile-time parities)
    for (int i = 2; i < 512; i += 2) {
        phaseW<false, false>(h1s[1], h2s[1], h3s[1], h1s[0], h2s[0], h3s[0],
                             layerid, bcol, g, wbyte, &xls[i * 17],
                             bv, w1f, Ih0, Ih1, Il0, Il1, Hh0, Hh1, Hl0, Hl1, zc);
        phaseW<false, false>(h1s[0], h2s[0], h3s[0], h1s[1], h2s[1], h3s[1],
                             layerid, bcol, g, wbyte, &xls[(i + 1) * 17],
                             bv, w1f, Ih0, Ih1, Il0, Il1, Hh0, Hh1, Hl0, Hl1, zc);
    }

    // drain: phase 512 (L2(511)->h2s[0], L3(510)->h3s[0]; L1 output finite, unused)
    phaseW<false, false>(h1s[1], h2s[1], h3s[1], h1s[0], h2s[0], h3s[0],
                         layerid, bcol, g, wbyte, &xls[512 * 17],
                         bv, w1f, Ih0, Ih1, Il0, Il1, Hh0, Hh1, Hl0, Hl1, zc);
    // drain: phase 513 (L3(511)->h3s[1]; other outputs finite, unused)
    phaseW<false, false>(h1s[0], h2s[0], h3s[0], h1s[1], h2s[1], h3s[1],
                         layerid, bcol, g, wbyte, &xls[513 * 17],
                         bv, w1f, Ih0, Ih1, Il0, Il1, Hh0, Hh1, Hl0, Hl1, zc);

    // ---- FC epilogue: out[b][o] = (h3_hi + h3_lo) @ Wfc^T + bfc ----
    if (w < 4) {
        const short* h3f = h3s[1];
        int o = (w << 2) | g;           // 0..15, valid < 10
        int b = bcol;
        if (o < 10) {
            float acc = bfc[o];
            for (int k = 0; k < 50; ++k)
                acc += (ldsR(h3f, b, k) + ldsR(h3f, b, 64 + k)) * Wfc[o * 50 + k];
            out[(size_t)(b0 + b) * 10 + o] = acc;
        }
    }
}

extern "C" void kernel_launch(void* const* d_in, const int* in_sizes, int n_in,
                              void* d_out, int out_size, void* d_ws, size_t ws_size,
                              hipStream_t stream) {
    const float* x    = (const float*)d_in[0];
    const float* Wih1 = (const float*)d_in[1];
    const float* Whh1 = (const float*)d_in[2];
    const float* bih1 = (const float*)d_in[3];
    const float* bhh1 = (const float*)d_in[4];
    const float* Wih2 = (const float*)d_in[5];
    const float* Whh2 = (const float*)d_in[6];
    const float* bih2 = (const float*)d_in[7];
    const float* bhh2 = (const float*)d_in[8];
    const float* Wih3 = (const float*)d_in[9];
    const float* Whh3 = (const float*)d_in[10];
    const float* bih3 = (const float*)d_in[11];
    const float* bhh3 = (const float*)d_in[12];
    const float* Wfc  = (const float*)d_in[13];
    const float* bfc  = (const float*)d_in[14];
    float* out = (float*)d_out;

    dim3 grid(256), block(768);   // 16 batch rows/block; 12 waves = layer x stripe
    hipLaunchKernelGGL(rnn3_kernel, grid, block, 0, stream,
                       x, Wih1, Whh1, bih1, bhh1,
                       Wih2, Whh2, bih2, bhh2,
                       Wih3, Whh3, bih3, bhh3,
                       Wfc, bfc, out);
}